// Round 1
// baseline (303.838 us; speedup 1.0000x reference)
//
#include <hip/hip_runtime.h>

#define N_NODES 1024
#define BATCH   128
#define D_IN    64
#define D_OUT   64
#define E_DIM   16

// ---------------- Kernel A: supports = softmax(relu(emb @ emb^T), axis=1) ----
__global__ __launch_bounds__(256) void k_supports(const float* __restrict__ emb,
                                                  float* __restrict__ sup) {
    const int n = blockIdx.x;
    const int t = threadIdx.x;
    __shared__ float en[E_DIM];
    __shared__ float red[4];
    if (t < E_DIM) en[t] = emb[n * E_DIM + t];
    __syncthreads();

    float sc[4];
    float mx = -1e30f;
#pragma unroll
    for (int r = 0; r < 4; ++r) {
        const int m = r * 256 + t;
        const float* em = &emb[m * E_DIM];
        float s = 0.f;
#pragma unroll
        for (int e = 0; e < E_DIM; ++e) s = fmaf(en[e], em[e], s);
        s = fmaxf(s, 0.f);   // relu
        sc[r] = s;
        mx = fmaxf(mx, s);
    }
    // wave (64-lane) max, then cross-wave via LDS
#pragma unroll
    for (int o = 32; o > 0; o >>= 1) mx = fmaxf(mx, __shfl_xor(mx, o));
    if ((t & 63) == 0) red[t >> 6] = mx;
    __syncthreads();
    mx = fmaxf(fmaxf(red[0], red[1]), fmaxf(red[2], red[3]));

    float sum = 0.f;
#pragma unroll
    for (int r = 0; r < 4; ++r) { sc[r] = __expf(sc[r] - mx); sum += sc[r]; }
#pragma unroll
    for (int o = 32; o > 0; o >>= 1) sum += __shfl_xor(sum, o);
    __syncthreads();                 // red[] reuse guard
    if ((t & 63) == 0) red[t >> 6] = sum;
    __syncthreads();
    sum = red[0] + red[1] + red[2] + red[3];
    const float inv = 1.f / sum;
#pragma unroll
    for (int r = 0; r < 4; ++r) sup[n * N_NODES + r * 256 + t] = sc[r] * inv;
}

// ---------------- Kernel B: per-node weights [N,64,64] and bias [N,64] ------
__global__ __launch_bounds__(256) void k_weights(const float* __restrict__ emb,
                                                 const float* __restrict__ wpool,
                                                 const float* __restrict__ bpool,
                                                 float* __restrict__ W,
                                                 float* __restrict__ bias) {
    const int n = blockIdx.x;
    const int t = threadIdx.x;
    __shared__ float en[E_DIM];
    if (t < E_DIM) en[t] = emb[n * E_DIM + t];
    __syncthreads();
#pragma unroll 4
    for (int r = 0; r < 16; ++r) {
        const int idx = r * 256 + t;
        float s = 0.f;
#pragma unroll
        for (int e = 0; e < E_DIM; ++e) s = fmaf(en[e], wpool[e * 4096 + idx], s);
        W[n * 4096 + idx] = s;
    }
    if (t < D_OUT) {
        float s = 0.f;
#pragma unroll
        for (int e = 0; e < E_DIM; ++e) s = fmaf(en[e], bpool[e * D_OUT + t], s);
        bias[n * D_OUT + t] = s;
    }
}

// ---------------- Kernel C: x_g = S @ X  (M=1024, K=1024, Ncols=B*64=8192) --
// x layout: x[b][m][c] at (b*1024+m)*64+c. Column index j = b*64 + c.
#define BM 128
#define BN 128
#define BK 16
#define XPAD 4

__global__ __launch_bounds__(256) void k_agg(const float* __restrict__ sup,
                                             const float* __restrict__ x,
                                             float* __restrict__ xg) {
    const int n0 = blockIdx.x * BM;
    const int j0 = blockIdx.y * BN;
    __shared__ float sT[BK][BM];          // sT[kk][i]  (S transposed tile)
    __shared__ float xt[BK][BN + XPAD];   // xt[kk][j]

    const int t = threadIdx.x;
    const int tr = t >> 4, tc = t & 15;

    float acc[8][8];
#pragma unroll
    for (int p = 0; p < 8; ++p)
#pragma unroll
        for (int q = 0; q < 8; ++q) acc[p][q] = 0.f;

    const int li  = t >> 1;          // 0..127 (S row within tile)
    const int lkb = (t & 1) * 8;     // 0 or 8 (S kk base)
    const int lkk = t >> 4;          // 0..15  (X kk)
    const int ljb = (t & 15) * 8;    // 0..120 (X col base, 8 contiguous c in one b)
    const int lb  = (j0 + ljb) >> 6;
    const int lc  = (j0 + ljb) & 63;

    for (int k0 = 0; k0 < N_NODES; k0 += BK) {
        {   // S tile: 128 rows x 16 kk
            const float* src = &sup[(n0 + li) * N_NODES + k0 + lkb];
            const float4 v0 = *(const float4*)src;
            const float4 v1 = *(const float4*)(src + 4);
            sT[lkb + 0][li] = v0.x; sT[lkb + 1][li] = v0.y;
            sT[lkb + 2][li] = v0.z; sT[lkb + 3][li] = v0.w;
            sT[lkb + 4][li] = v1.x; sT[lkb + 5][li] = v1.y;
            sT[lkb + 6][li] = v1.z; sT[lkb + 7][li] = v1.w;
        }
        {   // X tile: 16 kk x 128 j
            const int m = k0 + lkk;
            const float* src = &x[(lb * N_NODES + m) * 64 + lc];
            const float4 v0 = *(const float4*)src;
            const float4 v1 = *(const float4*)(src + 4);
            *(float4*)&xt[lkk][ljb]     = v0;
            *(float4*)&xt[lkk][ljb + 4] = v1;
        }
        __syncthreads();
#pragma unroll
        for (int kk = 0; kk < BK; ++kk) {
            float a[8], b[8];
            *(float4*)&a[0] = *(const float4*)&sT[kk][tr * 8];
            *(float4*)&a[4] = *(const float4*)&sT[kk][tr * 8 + 4];
            *(float4*)&b[0] = *(const float4*)&xt[kk][tc * 8];
            *(float4*)&b[4] = *(const float4*)&xt[kk][tc * 8 + 4];
#pragma unroll
            for (int p = 0; p < 8; ++p)
#pragma unroll
                for (int q = 0; q < 8; ++q)
                    acc[p][q] = fmaf(a[p], b[q], acc[p][q]);
        }
        __syncthreads();
    }
    // store: xg has same layout as x
#pragma unroll
    for (int p = 0; p < 8; ++p) {
        const int n = n0 + tr * 8 + p;
#pragma unroll
        for (int q = 0; q < 8; q += 4) {
            const int j = j0 + tc * 8 + q;
            const int b = j >> 6, c = j & 63;
            *(float4*)&xg[(b * N_NODES + n) * 64 + c] =
                make_float4(acc[p][q], acc[p][q + 1], acc[p][q + 2], acc[p][q + 3]);
        }
    }
}

// ---------------- Kernel D: out[b,n,:] = xg[b,n,:] @ W[n] + bias[n] ---------
__global__ __launch_bounds__(256) void k_out(const float* __restrict__ xg,
                                             const float* __restrict__ W,
                                             const float* __restrict__ bias,
                                             float* __restrict__ out) {
    const int n = blockIdx.x;
    const int t = threadIdx.x;
    __shared__ float Wl[D_IN][D_OUT];
    __shared__ float xl[4][D_IN];
#pragma unroll 4
    for (int r = 0; r < 16; ++r) {
        const int idx = r * 256 + t;
        ((float*)Wl)[idx] = W[n * 4096 + idx];
    }
    const int o  = t & 63;
    const int bl = t >> 6;
    const float bv = bias[n * 64 + o];
    for (int b0 = 0; b0 < BATCH; b0 += 4) {
        __syncthreads();   // covers W load on first iter + previous compute
        xl[bl][o] = xg[((b0 + bl) * N_NODES + n) * 64 + o];
        __syncthreads();
        float s = bv;
#pragma unroll
        for (int i = 0; i < D_IN; ++i) s = fmaf(xl[bl][i], Wl[i][o], s);
        out[((b0 + bl) * N_NODES + n) * 64 + o] = s;
    }
}

extern "C" void kernel_launch(void* const* d_in, const int* in_sizes, int n_in,
                              void* d_out, int out_size, void* d_ws, size_t ws_size,
                              hipStream_t stream) {
    const float* x     = (const float*)d_in[0];
    const float* emb   = (const float*)d_in[1];
    const float* wpool = (const float*)d_in[2];
    const float* bpool = (const float*)d_in[3];
    float* out = (float*)d_out;

    char* ws = (char*)d_ws;
    float* sup  = (float*)(ws);                              // 4 MiB
    float* W    = (float*)(ws + 4u  * 1024u * 1024u);        // 16 MiB
    float* bias = (float*)(ws + 20u * 1024u * 1024u);        // 256 KiB
    float* xg   = (float*)(ws + 21u * 1024u * 1024u);        // 32 MiB
    (void)in_sizes; (void)n_in; (void)out_size; (void)ws_size;

    k_supports<<<dim3(N_NODES), dim3(256), 0, stream>>>(emb, sup);
    k_weights<<<dim3(N_NODES), dim3(256), 0, stream>>>(emb, wpool, bpool, W, bias);
    dim3 gc(N_NODES / BM, (BATCH * 64) / BN);   // (8, 64)
    k_agg<<<gc, dim3(256), 0, stream>>>(sup, x, xg);
    k_out<<<dim3(N_NODES), dim3(256), 0, stream>>>(xg, W, bias, out);
}

// Round 2
// 83.219 us; speedup vs baseline: 3.6511x; 3.6511x over previous
//
#include <hip/hip_runtime.h>

#define N_NODES 1024
#define BATCH   128
#define E_DIM   16

typedef __attribute__((ext_vector_type(8))) short bf16x8;
typedef __attribute__((ext_vector_type(4))) float f32x4;

__device__ __forceinline__ unsigned short f2bf(float f) {
    union { float f; unsigned int u; } v; v.f = f;
    unsigned int u = v.u;
    u += 0x7FFFu + ((u >> 16) & 1u);
    return (unsigned short)(u >> 16);
}

__device__ __forceinline__ void gload_lds16(const void* g, void* l) {
    __builtin_amdgcn_global_load_lds(
        (const __attribute__((address_space(1))) unsigned int*)g,
        (__attribute__((address_space(3))) unsigned int*)l, 16, 0, 0);
}

// ---------------- A: supports = softmax(relu(emb emb^T)) -> bf16 ------------
__global__ __launch_bounds__(256) void k_supports(const float* __restrict__ emb,
                                                  unsigned short* __restrict__ sup) {
    const int n = blockIdx.x;
    const int t = threadIdx.x;
    __shared__ float en[E_DIM];
    __shared__ float red[4];
    if (t < E_DIM) en[t] = emb[n * E_DIM + t];
    __syncthreads();

    float sc[4];
    float mx = -1e30f;
#pragma unroll
    for (int r = 0; r < 4; ++r) {
        const float* em = &emb[(r * 256 + t) * E_DIM];
        float s = 0.f;
#pragma unroll
        for (int e = 0; e < E_DIM; ++e) s = fmaf(en[e], em[e], s);
        s = fmaxf(s, 0.f);
        sc[r] = s;
        mx = fmaxf(mx, s);
    }
#pragma unroll
    for (int o = 32; o > 0; o >>= 1) mx = fmaxf(mx, __shfl_xor(mx, o));
    if ((t & 63) == 0) red[t >> 6] = mx;
    __syncthreads();
    mx = fmaxf(fmaxf(red[0], red[1]), fmaxf(red[2], red[3]));

    float sum = 0.f;
#pragma unroll
    for (int r = 0; r < 4; ++r) { sc[r] = __expf(sc[r] - mx); sum += sc[r]; }
#pragma unroll
    for (int o = 32; o > 0; o >>= 1) sum += __shfl_xor(sum, o);
    __syncthreads();
    if ((t & 63) == 0) red[t >> 6] = sum;
    __syncthreads();
    sum = red[0] + red[1] + red[2] + red[3];
    const float inv = 1.f / sum;
#pragma unroll
    for (int r = 0; r < 4; ++r) sup[n * N_NODES + r * 256 + t] = f2bf(sc[r] * inv);
}

// ---------------- B: xbt[j=b*64+c][m] = bf16(x[b][m][c]) --------------------
__global__ __launch_bounds__(256) void k_xt(const float* __restrict__ x,
                                            unsigned short* __restrict__ xbt) {
    __shared__ __align__(16) unsigned short xt[64 * 72];   // [c][m], pitch 72
    const int t  = threadIdx.x;
    const int b  = blockIdx.y;
    const int m0 = blockIdx.x * 64;
    const int c  = t & 63, mr = t >> 6;
    const float* src = x + ((long)b * N_NODES + m0 + mr) * 64 + c;
#pragma unroll
    for (int i = 0; i < 16; ++i)
        xt[c * 72 + mr + i * 4] = f2bf(src[(long)i * 4 * 64]);
    __syncthreads();
    const int cc = t >> 2, mb = (t & 3) * 16;
    unsigned short* dst = xbt + ((long)b * 64 + cc) * N_NODES + m0 + mb;
    *(bf16x8*)(dst)     = *(const bf16x8*)(&xt[cc * 72 + mb]);
    *(bf16x8*)(dst + 8) = *(const bf16x8*)(&xt[cc * 72 + mb + 8]);
}

// ---------------- C: Wt[n][o][i] bf16, bias[n][o] f32 -----------------------
__global__ __launch_bounds__(256) void k_weights(const float* __restrict__ emb,
                                                 const float* __restrict__ wpool,
                                                 const float* __restrict__ bpool,
                                                 unsigned short* __restrict__ Wt,
                                                 float* __restrict__ bias) {
    const int n = blockIdx.x;
    const int t = threadIdx.x;
    __shared__ float en[E_DIM];
    __shared__ float wl[64 * 65];   // [i][o], pitch 65
    if (t < E_DIM) en[t] = emb[n * E_DIM + t];
    __syncthreads();
#pragma unroll 4
    for (int r = 0; r < 16; ++r) {
        const int idx = r * 256 + t;    // i = idx>>6, o = idx&63
        float s = 0.f;
#pragma unroll
        for (int e = 0; e < E_DIM; ++e) s = fmaf(en[e], wpool[e * 4096 + idx], s);
        wl[(idx >> 6) * 65 + (idx & 63)] = s;
    }
    if (t < 64) {
        float s = 0.f;
#pragma unroll
        for (int e = 0; e < E_DIM; ++e) s = fmaf(en[e], bpool[e * 64 + t], s);
        bias[n * 64 + t] = s;
    }
    __syncthreads();
#pragma unroll 4
    for (int r = 0; r < 16; ++r) {
        const int idx = r * 256 + t;    // o = idx>>6, i = idx&63
        Wt[(long)n * 4096 + idx] = f2bf(wl[(idx & 63) * 65 + (idx >> 6)]);
    }
}

// ---------------- D: xg = S @ X  via bf16 MFMA ------------------------------
// A = S [1024 n][1024 m] bf16, B^T = xbt [8192 j][1024 m] bf16,
// C = xg [1024 n][8192 j] bf16.  128x128 tile, BK=32, double-buffered LDS.
// LDS per buffer: A planes [4 kblk][128 row][8 bf16] (8KB) + B same (8KB).
__global__ __launch_bounds__(256, 2) void k_agg(const unsigned short* __restrict__ S,
                                                const unsigned short* __restrict__ Bt,
                                                unsigned short* __restrict__ xg) {
    __shared__ __align__(16) char lds[32768];
    const int t = threadIdx.x;
    const int lane = t & 63, wid = t >> 6;
    const int n0 = blockIdx.x * 128, j0 = blockIdx.y * 128;
    const int wr = wid >> 1, wc = wid & 1;

    f32x4 acc[4][4];
#pragma unroll
    for (int m = 0; m < 4; ++m)
#pragma unroll
        for (int n = 0; n < 4; ++n) acc[m][n] = f32x4{0.f, 0.f, 0.f, 0.f};

    const unsigned short* baseA0 = S  + (long)(n0 +      lane) * 1024 + wid * 8;
    const unsigned short* baseA1 = S  + (long)(n0 + 64 + lane) * 1024 + wid * 8;
    const unsigned short* baseB0 = Bt + (long)(j0 +      lane) * 1024 + wid * 8;
    const unsigned short* baseB1 = Bt + (long)(j0 + 64 + lane) * 1024 + wid * 8;
    const int dA0 = (2 * wid + 0) * 1024, dA1 = (2 * wid + 1) * 1024;

#define STAGE(buf, kt) do {                                   \
        const int ko = (kt) * 32;                             \
        gload_lds16(baseA0 + ko, (buf) + dA0);                \
        gload_lds16(baseA1 + ko, (buf) + dA1);                \
        gload_lds16(baseB0 + ko, (buf) + 8192 + dA0);         \
        gload_lds16(baseB1 + ko, (buf) + 8192 + dA1);         \
    } while (0)

    int aoff[4], boff[4];
#pragma unroll
    for (int m = 0; m < 4; ++m)
        aoff[m] = (lane >> 4) * 2048 + (wr * 64 + m * 16 + (lane & 15)) * 16;
#pragma unroll
    for (int n = 0; n < 4; ++n)
        boff[n] = 8192 + (lane >> 4) * 2048 + (wc * 64 + n * 16 + (lane & 15)) * 16;

    char* cur = lds;
    char* nxt = lds + 16384;
    STAGE(cur, 0);
    __syncthreads();
    for (int kt = 0; kt < 32; ++kt) {
        if (kt + 1 < 32) STAGE(nxt, kt + 1);
        bf16x8 a[4], b[4];
#pragma unroll
        for (int m = 0; m < 4; ++m) a[m] = *(const bf16x8*)(cur + aoff[m]);
#pragma unroll
        for (int n = 0; n < 4; ++n) b[n] = *(const bf16x8*)(cur + boff[n]);
#pragma unroll
        for (int m = 0; m < 4; ++m)
#pragma unroll
            for (int n = 0; n < 4; ++n)
                acc[m][n] = __builtin_amdgcn_mfma_f32_16x16x32_bf16(a[m], b[n], acc[m][n], 0, 0, 0);
        __syncthreads();
        char* tmp = cur; cur = nxt; nxt = tmp;
    }
#undef STAGE

    // epilogue: acc -> LDS (bf16, XOR-swizzled) -> coalesced global
    char* lb = lds;
#pragma unroll
    for (int m = 0; m < 4; ++m) {
        const int row0 = wr * 64 + m * 16 + (lane >> 4) * 4;
#pragma unroll
        for (int n = 0; n < 4; ++n) {
            const int colb = (wc * 64 + n * 16 + (lane & 15)) * 2;
#pragma unroll
            for (int r = 0; r < 4; ++r) {
                const int row = row0 + r;
                *(unsigned short*)(lb + row * 256 + (colb ^ ((row & 7) << 4))) =
                    f2bf(acc[m][n][r]);
            }
        }
    }
    __syncthreads();
#pragma unroll
    for (int i = 0; i < 8; ++i) {
        const int idx = i * 256 + t;       // 0..2047 chunks of 16B
        const int row = idx >> 4, cc = idx & 15;
        bf16x8 v = *(const bf16x8*)(lb + row * 256 + ((cc * 16) ^ ((row & 7) << 4)));
        *(bf16x8*)(xg + (long)(n0 + row) * 8192 + j0 + cc * 8) = v;
    }
}

// ---------------- E: out[b,n,o] = xg_n[b,:] @ W_n + bias_n ------------------
// A = xg[n] as [128 b][64 i] bf16, B = W_n via Wt[n][o][i], MFMA K=64.
__global__ __launch_bounds__(256) void k_out(const unsigned short* __restrict__ xg,
                                             const unsigned short* __restrict__ Wt,
                                             const float* __restrict__ bias,
                                             float* __restrict__ out) {
    __shared__ __align__(16) char lds[24576];   // xg_n 16KB (8 planes) | Wt_n 8KB
    const int t = threadIdx.x, lane = t & 63, wid = t >> 6;
    const int node = blockIdx.x;
    const unsigned short* gx = xg + (long)node * 8192;
    const unsigned short* gw = Wt + (long)node * 4096;
#pragma unroll
    for (int i = 0; i < 4; ++i) {
        const int c = wid * 4 + i;            // 0..15
        const int kblk = c >> 1, bh = c & 1;
        gload_lds16(gx + (bh * 64 + lane) * 64 + kblk * 8, lds + c * 1024);
    }
#pragma unroll
    for (int i = 0; i < 2; ++i) {
        const int c = wid * 2 + i;            // 0..7
        gload_lds16(gw + lane * 64 + c * 8, lds + 16384 + c * 1024);
    }
    __syncthreads();

    f32x4 acc[2][4];
#pragma unroll
    for (int m = 0; m < 2; ++m)
#pragma unroll
        for (int n = 0; n < 4; ++n) acc[m][n] = f32x4{0.f, 0.f, 0.f, 0.f};

#pragma unroll
    for (int s = 0; s < 2; ++s) {
        const int kb = s * 4 + (lane >> 4);
        bf16x8 a[2], b[4];
#pragma unroll
        for (int m = 0; m < 2; ++m)
            a[m] = *(const bf16x8*)(lds + kb * 2048 + (wid * 32 + m * 16 + (lane & 15)) * 16);
#pragma unroll
        for (int n = 0; n < 4; ++n)
            b[n] = *(const bf16x8*)(lds + 16384 + kb * 1024 + (n * 16 + (lane & 15)) * 16);
#pragma unroll
        for (int m = 0; m < 2; ++m)
#pragma unroll
            for (int n = 0; n < 4; ++n)
                acc[m][n] = __builtin_amdgcn_mfma_f32_16x16x32_bf16(a[m], b[n], acc[m][n], 0, 0, 0);
    }

#pragma unroll
    for (int n = 0; n < 4; ++n) {
        const int o = n * 16 + (lane & 15);
        const float bv = bias[node * 64 + o];
#pragma unroll
        for (int m = 0; m < 2; ++m) {
            const int b0 = wid * 32 + m * 16 + (lane >> 4) * 4;
#pragma unroll
            for (int r = 0; r < 4; ++r)
                out[(long)(b0 + r) * 65536 + node * 64 + o] = acc[m][n][r] + bv;
        }
    }
}

extern "C" void kernel_launch(void* const* d_in, const int* in_sizes, int n_in,
                              void* d_out, int out_size, void* d_ws, size_t ws_size,
                              hipStream_t stream) {
    const float* x     = (const float*)d_in[0];
    const float* emb   = (const float*)d_in[1];
    const float* wpool = (const float*)d_in[2];
    const float* bpool = (const float*)d_in[3];
    float* out = (float*)d_out;

    char* ws = (char*)d_ws;
    unsigned short* sup  = (unsigned short*)(ws);                        // 2 MiB
    unsigned short* xbt  = (unsigned short*)(ws + (2u  << 20));          // 16 MiB
    unsigned short* Wt   = (unsigned short*)(ws + (18u << 20));          // 8 MiB
    float*          bias = (float*)         (ws + (26u << 20));          // 256 KiB
    unsigned short* xg   = (unsigned short*)(ws + (27u << 20));          // 16 MiB
    (void)in_sizes; (void)n_in; (void)out_size; (void)ws_size;

    k_supports<<<dim3(N_NODES), dim3(256), 0, stream>>>(emb, sup);
    k_xt<<<dim3(16, BATCH), dim3(256), 0, stream>>>(x, xbt);
    k_weights<<<dim3(N_NODES), dim3(256), 0, stream>>>(emb, wpool, bpool, Wt, bias);
    k_agg<<<dim3(8, 64), dim3(256), 0, stream>>>(sup, xbt, xg);
    k_out<<<dim3(N_NODES), dim3(256), 0, stream>>>(xg, Wt, bias, out);
}